// Round 1
// 306.460 us; speedup vs baseline: 1.0666x; 1.0666x over previous
//
#include <hip/hip_runtime.h>
#include <hip/hip_bf16.h>

// Problem constants: B=4, H=W=256, C=64, OC=64, K=3, PAD=1
#define FEAT_N (4*64*256*256)
#define OFFS_N (4*18*256*256)
#define WTF_N  (576*64)            // deform weights, bf16, MFMA-B-fragment order
#define WT2F_N (576*32)            // offset-conv weights, bf16 frags, N padded to 32

typedef __attribute__((ext_vector_type(8))) short short8;
typedef __attribute__((ext_vector_type(4))) float float4v;
typedef __attribute__((ext_vector_type(4))) unsigned uint4v;

__device__ __forceinline__ unsigned short f2bf(float f) {
    union { float f; unsigned u; } c; c.f = f;
    unsigned r = c.u + 0x7FFF + ((c.u >> 16) & 1);   // RNE
    return (unsigned short)(r >> 16);
}

__device__ __forceinline__ unsigned pack_bf16x2(float lo, float hi) {
    float2 v; v.x = lo; v.y = hi;
    __hip_bfloat162 h = __float22bfloat162_rn(v);
    union { __hip_bfloat162 h; unsigned u; } c; c.h = h;
    return c.u;
}

__device__ __forceinline__ float bf_lo(unsigned u) { return __uint_as_float(u << 16); }
__device__ __forceinline__ float bf_hi(unsigned u) { return __uint_as_float(u & 0xFFFF0000u); }

// ---------------------------------------------------------------------------
// Weight prep (unchanged): deform weights -> wtf (B-frags, 4 N-tiles);
// offset-conv weights -> wt2f (B-frags, 2 N-tiles, oc>=18 zero).
// ---------------------------------------------------------------------------
__global__ __launch_bounds__(256) void prep_weights(const float* __restrict__ dw,
                                                    const float* __restrict__ ow,
                                                    unsigned short* __restrict__ wtf,
                                                    unsigned short* __restrict__ wt2f) {
    int idx = blockIdx.x * 256 + threadIdx.x;
    if (idx < WTF_N) {
        int j    = idx & 7;
        int lane = (idx >> 3) & 63;
        int nt   = (idx >> 9) & 3;
        int ks   = idx >> 11;
        int k    = ks * 32 + ((lane >> 4) << 3) + j;
        int tap  = k >> 6;
        int ic   = k & 63;
        int n    = nt * 16 + (lane & 15);
        wtf[idx] = f2bf(dw[n * 576 + ic * 9 + tap]);
    }
    int i2 = idx - WTF_N;
    if (i2 >= 0 && i2 < WT2F_N) {
        int j    = i2 & 7;
        int lane = (i2 >> 3) & 63;
        int nt   = (i2 >> 9) & 1;
        int ks   = i2 >> 10;
        int k    = ks * 32 + ((lane >> 4) << 3) + j;
        int tap  = k >> 6;
        int ic   = k & 63;
        int n    = nt * 16 + (lane & 15);
        wt2f[i2] = (n < 18) ? f2bf(ow[n * 576 + ic * 9 + tap]) : (unsigned short)0;
    }
}

// ---------------------------------------------------------------------------
// conv1: x[4,3,256,256] * w + b -> featp, NHWC bf16:
// dword index for (b,y,x,cp) = ((b<<16)+(y<<8)+x)*32 + cp  (cp = channel pair,
// lo half = even channel). One row per block, 256 threads = 256 columns.
// Per-thread output = 32 contiguous dwords -> 8 dwordx4 stores.
// ---------------------------------------------------------------------------
__global__ __launch_bounds__(256) void conv1_kernel(const float* __restrict__ x,
                                                    const float* __restrict__ cw,
                                                    const float* __restrict__ cb,
                                                    unsigned short* __restrict__ featp) {
    __shared__ __align__(16) float wl[64 * 28];
    __shared__ float bl[64];
    const int tid = threadIdx.x;
    for (int i = tid; i < 64 * 28; i += 256) {
        int oc = i / 28;
        int t  = i - oc * 28;
        wl[i] = (t < 27) ? cw[oc * 27 + t] : 0.f;
    }
    if (tid < 64) bl[tid] = cb[tid];
    __syncthreads();

    const int bx = blockIdx.x;
    const int b  = bx >> 8;
    const int h  = bx & 255;
    const int w  = tid;

    float xr[3][3][3];
#pragma unroll
    for (int ic = 0; ic < 3; ic++) {
#pragma unroll
        for (int r = 0; r < 3; r++) {
            int row = h - 1 + r;
            bool rok = (unsigned)row < 256u;
#pragma unroll
            for (int j = 0; j < 3; j++) {
                int col = w - 1 + j;
                bool ok = rok && ((unsigned)col < 256u);
                xr[ic][r][j] = ok ? x[((b * 3 + ic) << 16) + (row << 8) + col] : 0.f;
            }
        }
    }

    unsigned* dst = (unsigned*)featp + ((((size_t)b << 16) + (h << 8) + w) << 5);
    for (int g = 0; g < 8; g++) {               // dynamic: keep code compact
        uint4v v;
#pragma unroll
        for (int q = 0; q < 4; q++) {
            const int ocp = 4 * g + q;
            float a0 = bl[2 * ocp], a1 = bl[2 * ocp + 1];
            const float* wp0 = &wl[(2 * ocp) * 28];
            const float* wp1 = wp0 + 28;
#pragma unroll
            for (int ic = 0; ic < 3; ic++)
#pragma unroll
                for (int i = 0; i < 3; i++)
#pragma unroll
                    for (int j = 0; j < 3; j++) {
                        float xv = xr[ic][i][j];
                        a0 += xv * wp0[ic * 9 + i * 3 + j];
                        a1 += xv * wp1[ic * 9 + i * 3 + j];
                    }
            v[q] = pack_bf16x2(a0, a1);
        }
        *(uint4v*)(dst + 4 * g) = v;
    }
}

// ---------------------------------------------------------------------------
// conv2: MFMA, A-frags read DIRECTLY from NHWC featp (no LDS, no barriers).
// Lane (lm,quad): m = px = lm, k-block = quad -> the 8 channels a lane needs
// per step are 16B contiguous at px*128B + step*64B + quad*16B.
// Block = 4 waves x 32 px = 128-px strip of one row.
// ---------------------------------------------------------------------------
__global__ __launch_bounds__(256) void conv2_kernel(const unsigned short* __restrict__ featp,
                                                    const unsigned short* __restrict__ wt2f,
                                                    const float* __restrict__ ob,
                                                    float* __restrict__ offs) {
    const int tid  = threadIdx.x;
    const int lane = tid & 63;
    const int wave = tid >> 6;
    const int lm   = lane & 15;
    const int quad = lane >> 4;

    const int bx = blockIdx.x;
    const int strip = ((bx & 7) << 8) | (bx >> 3);
    const int wo_base = (strip & 1) << 7;
    const int ho = (strip >> 1) & 255;
    const int b  = strip >> 9;

    const unsigned* fpq = (const unsigned*)featp + ((size_t)b << 21) + quad * 4;

    float4v acc[2][2];
#pragma unroll
    for (int mt = 0; mt < 2; mt++)
#pragma unroll
        for (int nt = 0; nt < 2; nt++) acc[mt][nt] = (float4v)0.f;

#pragma unroll
    for (int ky = 0; ky < 3; ky++) {
        const int row = ho - 1 + ky;
        const bool rok = (unsigned)row < 256u;
#pragma unroll
        for (int kx = 0; kx < 3; kx++) {
            const int tap = ky * 3 + kx;
            short8 bfr[2][2];
            const unsigned short* wp = wt2f + (size_t)(tap * 2) * 1024 + lane * 8;
#pragma unroll
            for (int st = 0; st < 2; st++) {
                bfr[st][0] = *(const short8*)(wp + st * 1024);
                bfr[st][1] = *(const short8*)(wp + st * 1024 + 512);
            }
#pragma unroll
            for (int mt = 0; mt < 2; mt++) {
                const int col = wo_base + wave * 32 + mt * 16 + lm + kx - 1;
                uint4v a0 = 0, a1 = 0;
                if (rok && (unsigned)col < 256u) {
                    const unsigned* p = fpq + (((row << 8) + col) << 5);
                    a0 = *(const uint4v*)p;
                    a1 = *(const uint4v*)(p + 16);
                }
                union { short8 v; uint4v u; } f0, f1;
                f0.u = a0; f1.u = a1;
                acc[mt][0] = __builtin_amdgcn_mfma_f32_16x16x32_bf16(f0.v, bfr[0][0], acc[mt][0], 0, 0, 0);
                acc[mt][1] = __builtin_amdgcn_mfma_f32_16x16x32_bf16(f0.v, bfr[0][1], acc[mt][1], 0, 0, 0);
                acc[mt][0] = __builtin_amdgcn_mfma_f32_16x16x32_bf16(f1.v, bfr[1][0], acc[mt][0], 0, 0, 0);
                acc[mt][1] = __builtin_amdgcn_mfma_f32_16x16x32_bf16(f1.v, bfr[1][1], acc[mt][1], 0, 0, 0);
            }
        }
    }

#pragma unroll
    for (int nt = 0; nt < 2; nt++) {
        int oc = nt * 16 + lm;
        if (oc < 18) {
            float bv = ob[oc];
            float* op = offs + (((size_t)(b * 18 + oc)) << 16) + (ho << 8)
                      + wo_base + wave * 32 + quad * 4;
#pragma unroll
            for (int mt = 0; mt < 2; mt++) {
                float4 v = {acc[mt][nt][0] + bv, acc[mt][nt][1] + bv,
                            acc[mt][nt][2] + bv, acc[mt][nt][3] + bv};
                *(float4*)(op + mt * 16) = v;
            }
        }
    }
}

// ---------------------------------------------------------------------------
// deform conv: NHWC featp, register-direct bilinear gathers.
// Lane (lm,quad) gathers for its px (lm, per mt) the 4 bilinear corners,
// 16B (8 channels = its own A-frag k-block) per corner per step -> combine in
// f32 -> pack -> MFMA A operand directly. NO LDS. Cross-tap double-buffered
// gather pipeline (G[mt] filled one tap ahead).
// ---------------------------------------------------------------------------
__global__ __launch_bounds__(256, 3) void deform_kernel(const unsigned short* __restrict__ featp,
                                                        const float* __restrict__ offs,
                                                        const unsigned short* __restrict__ wtf,
                                                        const float* __restrict__ db,
                                                        float* __restrict__ out) {
    const int tid  = threadIdx.x;
    const int lane = tid & 63;
    const int wave = tid >> 6;
    const int lm   = lane & 15;
    const int quad = lane >> 4;

    const int bx = blockIdx.x;
    const int strip = ((bx & 7) << 8) | (bx >> 3);
    const int wo_base = (strip & 1) << 7;
    const int ho = (strip >> 1) & 255;
    const int b  = strip >> 9;

    const int wo0 = wo_base + wave * 32 + lm;       // mt=0 pixel; mt=1 is +16

    const float* opb = offs + (((size_t)b * 18) << 16) + (ho << 8) + wo0;
    const unsigned* fpq = (const unsigned*)featp + ((size_t)b << 21) + quad * 4;

    float4v acc[2][4];
#pragma unroll
    for (int mt = 0; mt < 2; mt++)
#pragma unroll
        for (int nt = 0; nt < 4; nt++) acc[mt][nt] = (float4v)0.f;

    float w00[2], w01[2], w10[2], w11[2];
    unsigned e00[2], e01[2], e10[2], e11[2];
    uint4v G[2][4][2];                  // [mt][corner][step], 16B each

    union AFU { short8 v; unsigned u[4]; };

#define COORDS(MT, KY, KX, OY, OX)                                               \
    {                                                                            \
        float sy = (float)(ho - 1 + (KY)) + (OY);                                \
        float sx = (float)(wo0 + (MT) * 16 - 1 + (KX)) + (OX);                   \
        float y0f = floorf(sy), x0f = floorf(sx);                                \
        float dy = sy - y0f, dx = sx - x0f;                                      \
        int y0 = (int)y0f, x0 = (int)x0f;                                        \
        float wy0 = ((unsigned)y0 < 256u) ? (1.f - dy) : 0.f;                    \
        float wy1 = ((unsigned)(y0 + 1) < 256u) ? dy : 0.f;                      \
        float wx0 = ((unsigned)x0 < 256u) ? (1.f - dx) : 0.f;                    \
        float wx1 = ((unsigned)(x0 + 1) < 256u) ? dx : 0.f;                      \
        int yb0 = y0 < 0 ? 0 : (y0 > 255 ? 255 : y0);                            \
        int yb1 = (y0 + 1) < 0 ? 0 : ((y0 + 1) > 255 ? 255 : (y0 + 1));          \
        int xb0 = x0 < 0 ? 0 : (x0 > 255 ? 255 : x0);                            \
        int xb1 = (x0 + 1) < 0 ? 0 : ((x0 + 1) > 255 ? 255 : (x0 + 1));          \
        w00[MT] = wy0 * wx0; w01[MT] = wy0 * wx1;                                \
        w10[MT] = wy1 * wx0; w11[MT] = wy1 * wx1;                                \
        e00[MT] = ((yb0 << 8) + xb0) << 5; e01[MT] = ((yb0 << 8) + xb1) << 5;    \
        e10[MT] = ((yb1 << 8) + xb0) << 5; e11[MT] = ((yb1 << 8) + xb1) << 5;    \
    }

#define ISSUE(MT)                                                                \
    {                                                                            \
        G[MT][0][0] = *(const uint4v*)(fpq + e00[MT]);                           \
        G[MT][0][1] = *(const uint4v*)(fpq + e00[MT] + 16);                      \
        G[MT][1][0] = *(const uint4v*)(fpq + e01[MT]);                           \
        G[MT][1][1] = *(const uint4v*)(fpq + e01[MT] + 16);                      \
        G[MT][2][0] = *(const uint4v*)(fpq + e10[MT]);                           \
        G[MT][2][1] = *(const uint4v*)(fpq + e10[MT] + 16);                      \
        G[MT][3][0] = *(const uint4v*)(fpq + e11[MT]);                           \
        G[MT][3][1] = *(const uint4v*)(fpq + e11[MT] + 16);                      \
    }

#define COMBINE(MT, AF)                                                          \
    _Pragma("unroll")                                                            \
    for (int st = 0; st < 2; st++) {                                             \
        _Pragma("unroll")                                                        \
        for (int j = 0; j < 4; j++) {                                            \
            unsigned u0 = G[MT][0][st][j], u1 = G[MT][1][st][j];                 \
            unsigned u2 = G[MT][2][st][j], u3 = G[MT][3][st][j];                 \
            float g0 = w00[MT] * bf_lo(u0) + w01[MT] * bf_lo(u1)                 \
                     + w10[MT] * bf_lo(u2) + w11[MT] * bf_lo(u3);                \
            float g1 = w00[MT] * bf_hi(u0) + w01[MT] * bf_hi(u1)                 \
                     + w10[MT] * bf_hi(u2) + w11[MT] * bf_hi(u3);                \
            AF[st].u[j] = pack_bf16x2(g0, g1);                                   \
        }                                                                        \
    }

#define MFMA_MT(MT, AF)                                                          \
    _Pragma("unroll")                                                            \
    for (int nt = 0; nt < 4; nt++)                                               \
        acc[MT][nt] = __builtin_amdgcn_mfma_f32_16x16x32_bf16(                   \
            AF[0].v, bfr[0][nt], acc[MT][nt], 0, 0, 0);                          \
    _Pragma("unroll")                                                            \
    for (int nt = 0; nt < 4; nt++)                                               \
        acc[MT][nt] = __builtin_amdgcn_mfma_f32_16x16x32_bf16(                   \
            AF[1].v, bfr[1][nt], acc[MT][nt], 0, 0, 0);

    // Prologue: gather tap 0 for both mt
    {
        float oy0 = opb[0],  ox0 = opb[65536];
        float oy1 = opb[16], ox1 = opb[65536 + 16];
        COORDS(0, 0, 0, oy0, ox0);
        ISSUE(0);
        COORDS(1, 0, 0, oy1, ox1);
        ISSUE(1);
    }

    for (int tap = 0; tap < 9; ++tap) {
        float ny0 = 0.f, nx0 = 0.f, ny1 = 0.f, nx1 = 0.f;
        if (tap < 8) {                                  // next-tap offsets, early
            const float* p = opb + ((size_t)(2 * tap + 2) << 16);
            ny0 = p[0]; ny1 = p[16];
            nx0 = p[65536]; nx1 = p[65536 + 16];
        }
        short8 bfr[2][4];                               // B-frags, both steps
        {
            const unsigned short* wp = wtf + (size_t)tap * 4096 + lane * 8;
#pragma unroll
            for (int nt = 0; nt < 4; nt++) {
                bfr[0][nt] = *(const short8*)(wp + (nt << 9));
                bfr[1][nt] = *(const short8*)(wp + 2048 + (nt << 9));
            }
        }
        const int tn  = tap + 1;
        const int nky = (int)((unsigned)tn / 3u);
        const int nkx = tn - 3 * nky;

        AFU af[2];
        COMBINE(0, af);                                 // G0 issued last tap
        MFMA_MT(0, af);
        if (tap < 8) { COORDS(0, nky, nkx, ny0, nx0); ISSUE(0); }
        COMBINE(1, af);                                 // G1 issued last tap
        MFMA_MT(1, af);
        if (tap < 8) { COORDS(1, nky, nkx, ny1, nx1); ISSUE(1); }
    }

#pragma unroll
    for (int nt = 0; nt < 4; nt++) {
        int oc = nt * 16 + lm;
        float bv = db[oc];
        float* op = out + (((size_t)(b * 64 + oc)) << 16) + (ho << 8)
                  + wo_base + wave * 32 + quad * 4;
#pragma unroll
        for (int mt = 0; mt < 2; mt++) {
            float4 v = {acc[mt][nt][0] + bv, acc[mt][nt][1] + bv,
                        acc[mt][nt][2] + bv, acc[mt][nt][3] + bv};
            *(float4*)(op + mt * 16) = v;
        }
    }
#undef COORDS
#undef ISSUE
#undef COMBINE
#undef MFMA_MT
}

// ---------------------------------------------------------------------------
extern "C" void kernel_launch(void* const* d_in, const int* in_sizes, int n_in,
                              void* d_out, int out_size, void* d_ws, size_t ws_size,
                              hipStream_t stream) {
    const float* x  = (const float*)d_in[0];
    const float* cw = (const float*)d_in[1];
    const float* cb = (const float*)d_in[2];
    const float* ow = (const float*)d_in[3];
    const float* ob = (const float*)d_in[4];
    const float* dw = (const float*)d_in[5];
    const float* db = (const float*)d_in[6];
    float* out = (float*)d_out;

    unsigned short* featp = (unsigned short*)d_ws;       // 33.5 MB bf16 NHWC
    float* offsb = (float*)(featp + FEAT_N);             // 18 MB
    unsigned short* wtf  = (unsigned short*)(offsb + OFFS_N);  // 72 KB
    unsigned short* wt2f = wtf + WTF_N;                  // 36 KB

    prep_weights<<<216, 256, 0, stream>>>(dw, ow, wtf, wt2f);
    conv1_kernel<<<1024, 256, 0, stream>>>(x, cw, cb, featp);
    conv2_kernel<<<2048, 256, 0, stream>>>(featp, wt2f, ob, offsb);
    deform_kernel<<<2048, 256, 0, stream>>>(featp, offsb, wtf, db, out);
}

// Round 4
// 301.926 us; speedup vs baseline: 1.0826x; 1.0150x over previous
//
#include <hip/hip_runtime.h>
#include <hip/hip_bf16.h>

// Problem constants: B=4, H=W=256, C=64, OC=64, K=3, PAD=1
#define FEAT_N (4*64*256*256)
#define OFFS_N (4*18*256*256)
#define WTF_N  (576*64)            // deform weights, bf16, MFMA-B-fragment order
#define WT2F_N (576*32)            // offset-conv weights, bf16 frags, N padded to 32

typedef __attribute__((ext_vector_type(8))) short short8;
typedef __attribute__((ext_vector_type(4))) float float4v;
typedef __attribute__((ext_vector_type(4))) unsigned uint4v;

__device__ __forceinline__ unsigned short f2bf(float f) {
    union { float f; unsigned u; } c; c.f = f;
    unsigned r = c.u + 0x7FFF + ((c.u >> 16) & 1);   // RNE
    return (unsigned short)(r >> 16);
}

__device__ __forceinline__ unsigned pack_bf16x2(float lo, float hi) {
    float2 v; v.x = lo; v.y = hi;
    __hip_bfloat162 h = __float22bfloat162_rn(v);
    union { __hip_bfloat162 h; unsigned u; } c; c.h = h;
    return c.u;
}

__device__ __forceinline__ float bf_lo(unsigned u) { return __uint_as_float(u << 16); }
__device__ __forceinline__ float bf_hi(unsigned u) { return __uint_as_float(u & 0xFFFF0000u); }

// ---------------------------------------------------------------------------
// Weight prep (EXACT R1): deform weights -> wtf (B-frags, 4 N-tiles);
// offset-conv weights -> wt2f (B-frags, 2 N-tiles, oc>=18 zero).
// ---------------------------------------------------------------------------
__global__ __launch_bounds__(256) void prep_weights(const float* __restrict__ dw,
                                                    const float* __restrict__ ow,
                                                    unsigned short* __restrict__ wtf,
                                                    unsigned short* __restrict__ wt2f) {
    int idx = blockIdx.x * 256 + threadIdx.x;
    if (idx < WTF_N) {
        int j    = idx & 7;
        int lane = (idx >> 3) & 63;
        int nt   = (idx >> 9) & 3;
        int ks   = idx >> 11;
        int k    = ks * 32 + ((lane >> 4) << 3) + j;
        int tap  = k >> 6;
        int ic   = k & 63;
        int n    = nt * 16 + (lane & 15);
        wtf[idx] = f2bf(dw[n * 576 + ic * 9 + tap]);
    }
    int i2 = idx - WTF_N;
    if (i2 >= 0 && i2 < WT2F_N) {
        int j    = i2 & 7;
        int lane = (i2 >> 3) & 63;
        int nt   = (i2 >> 9) & 1;
        int ks   = i2 >> 10;
        int k    = ks * 32 + ((lane >> 4) << 3) + j;
        int tap  = k >> 6;
        int ic   = k & 63;
        int n    = nt * 16 + (lane & 15);
        wt2f[i2] = (n < 18) ? f2bf(ow[n * 576 + ic * 9 + tap]) : (unsigned short)0;
    }
}

// ---------------------------------------------------------------------------
// conv1 (EXACT R1, known-pass): x[4,3,256,256] * w + b -> featp, NHWC bf16:
// dword index for (b,y,x,cp) = ((b<<16)+(y<<8)+x)*32 + cp  (cp = channel pair,
// lo half = even channel). One row per block, 256 threads = 256 columns.
// ---------------------------------------------------------------------------
__global__ __launch_bounds__(256) void conv1_kernel(const float* __restrict__ x,
                                                    const float* __restrict__ cw,
                                                    const float* __restrict__ cb,
                                                    unsigned short* __restrict__ featp) {
    __shared__ __align__(16) float wl[64 * 28];
    __shared__ float bl[64];
    const int tid = threadIdx.x;
    for (int i = tid; i < 64 * 28; i += 256) {
        int oc = i / 28;
        int t  = i - oc * 28;
        wl[i] = (t < 27) ? cw[oc * 27 + t] : 0.f;
    }
    if (tid < 64) bl[tid] = cb[tid];
    __syncthreads();

    const int bx = blockIdx.x;
    const int b  = bx >> 8;
    const int h  = bx & 255;
    const int w  = tid;

    float xr[3][3][3];
#pragma unroll
    for (int ic = 0; ic < 3; ic++) {
#pragma unroll
        for (int r = 0; r < 3; r++) {
            int row = h - 1 + r;
            bool rok = (unsigned)row < 256u;
#pragma unroll
            for (int j = 0; j < 3; j++) {
                int col = w - 1 + j;
                bool ok = rok && ((unsigned)col < 256u);
                xr[ic][r][j] = ok ? x[((b * 3 + ic) << 16) + (row << 8) + col] : 0.f;
            }
        }
    }

    unsigned* dst = (unsigned*)featp + ((((size_t)b << 16) + (h << 8) + w) << 5);
    for (int g = 0; g < 8; g++) {               // dynamic: keep code compact
        uint4v v;
#pragma unroll
        for (int q = 0; q < 4; q++) {
            const int ocp = 4 * g + q;
            float a0 = bl[2 * ocp], a1 = bl[2 * ocp + 1];
            const float* wp0 = &wl[(2 * ocp) * 28];
            const float* wp1 = wp0 + 28;
#pragma unroll
            for (int ic = 0; ic < 3; ic++)
#pragma unroll
                for (int i = 0; i < 3; i++)
#pragma unroll
                    for (int j = 0; j < 3; j++) {
                        float xv = xr[ic][i][j];
                        a0 += xv * wp0[ic * 9 + i * 3 + j];
                        a1 += xv * wp1[ic * 9 + i * 3 + j];
                    }
            v[q] = pack_bf16x2(a0, a1);
        }
        *(uint4v*)(dst + 4 * g) = v;
    }
}

// ---------------------------------------------------------------------------
// conv2: R1 structure + 1-tap A-prefetch pipeline (the ONLY change this
// round). Same guarded loads, same addressing (<<5 px stride, +16 plane),
// same MFMA/bfr/store code as R1 — only the load of tap t+1 is issued
// before the MFMAs of tap t, hiding L2/L3 latency under compute.
// ---------------------------------------------------------------------------
__global__ __launch_bounds__(256) void conv2_kernel(const unsigned short* __restrict__ featp,
                                                    const unsigned short* __restrict__ wt2f,
                                                    const float* __restrict__ ob,
                                                    float* __restrict__ offs) {
    const int tid  = threadIdx.x;
    const int lane = tid & 63;
    const int wave = tid >> 6;
    const int lm   = lane & 15;
    const int quad = lane >> 4;

    const int bx = blockIdx.x;
    const int strip = ((bx & 7) << 8) | (bx >> 3);
    const int wo_base = (strip & 1) << 7;
    const int ho = (strip >> 1) & 255;
    const int b  = strip >> 9;

    const unsigned* fpq = (const unsigned*)featp + ((size_t)b << 21) + quad * 4;
    const int colb = wo_base + wave * 32 + lm;

    float4v acc[2][2];
#pragma unroll
    for (int mt = 0; mt < 2; mt++)
#pragma unroll
        for (int nt = 0; nt < 2; nt++) acc[mt][nt] = (float4v)0.f;

    uint4v A[2][2];   // [mt][half]: current tap's A-frag data

#define C2LOAD(KY, KX, DST)                                                      \
    {                                                                            \
        const int row = ho - 1 + (KY);                                           \
        const bool rok = (unsigned)row < 256u;                                   \
        _Pragma("unroll")                                                        \
        for (int mt = 0; mt < 2; mt++) {                                         \
            const int col = colb + mt * 16 + (KX) - 1;                           \
            DST[mt][0] = (uint4v)0;                                              \
            DST[mt][1] = (uint4v)0;                                              \
            if (rok && (unsigned)col < 256u) {                                   \
                const unsigned* p = fpq + (((row << 8) + col) << 5);             \
                DST[mt][0] = *(const uint4v*)p;                                  \
                DST[mt][1] = *(const uint4v*)(p + 16);                           \
            }                                                                    \
        }                                                                        \
    }

    C2LOAD(0, 0, A);

#pragma unroll
    for (int tap = 0; tap < 9; tap++) {
        short8 bfr[2][2];
        const unsigned short* wp = wt2f + (size_t)(tap * 2) * 1024 + lane * 8;
#pragma unroll
        for (int st = 0; st < 2; st++) {
            bfr[st][0] = *(const short8*)(wp + st * 1024);
            bfr[st][1] = *(const short8*)(wp + st * 1024 + 512);
        }
        uint4v N[2][2];
        if (tap < 8) {
            const int tn  = tap + 1;
            const int tky = tn / 3;
            const int tkx = tn - 3 * tky;
            C2LOAD(tky, tkx, N);
        }
#pragma unroll
        for (int mt = 0; mt < 2; mt++) {
            union { short8 v; uint4v u; } f0, f1;
            f0.u = A[mt][0]; f1.u = A[mt][1];
            acc[mt][0] = __builtin_amdgcn_mfma_f32_16x16x32_bf16(f0.v, bfr[0][0], acc[mt][0], 0, 0, 0);
            acc[mt][1] = __builtin_amdgcn_mfma_f32_16x16x32_bf16(f0.v, bfr[0][1], acc[mt][1], 0, 0, 0);
            acc[mt][0] = __builtin_amdgcn_mfma_f32_16x16x32_bf16(f1.v, bfr[1][0], acc[mt][0], 0, 0, 0);
            acc[mt][1] = __builtin_amdgcn_mfma_f32_16x16x32_bf16(f1.v, bfr[1][1], acc[mt][1], 0, 0, 0);
        }
        if (tap < 8) {
#pragma unroll
            for (int mt = 0; mt < 2; mt++) {
                A[mt][0] = N[mt][0];
                A[mt][1] = N[mt][1];
            }
        }
    }
#undef C2LOAD

#pragma unroll
    for (int nt = 0; nt < 2; nt++) {
        int oc = nt * 16 + lm;
        if (oc < 18) {
            float bv = ob[oc];
            float* op = offs + (((size_t)(b * 18 + oc)) << 16) + (ho << 8)
                      + wo_base + wave * 32 + quad * 4;
#pragma unroll
            for (int mt = 0; mt < 2; mt++) {
                float4 v = {acc[mt][nt][0] + bv, acc[mt][nt][1] + bv,
                            acc[mt][nt][2] + bv, acc[mt][nt][3] + bv};
                *(float4*)(op + mt * 16) = v;
            }
        }
    }
}

// ---------------------------------------------------------------------------
// deform conv (EXACT R1, known-pass): NHWC featp, register-direct bilinear
// gathers, mt-loop, G[2][4][2] cross-tap pipeline, 2048 blocks.
// ---------------------------------------------------------------------------
__global__ __launch_bounds__(256, 3) void deform_kernel(const unsigned short* __restrict__ featp,
                                                        const float* __restrict__ offs,
                                                        const unsigned short* __restrict__ wtf,
                                                        const float* __restrict__ db,
                                                        float* __restrict__ out) {
    const int tid  = threadIdx.x;
    const int lane = tid & 63;
    const int wave = tid >> 6;
    const int lm   = lane & 15;
    const int quad = lane >> 4;

    const int bx = blockIdx.x;
    const int strip = ((bx & 7) << 8) | (bx >> 3);
    const int wo_base = (strip & 1) << 7;
    const int ho = (strip >> 1) & 255;
    const int b  = strip >> 9;

    const int wo0 = wo_base + wave * 32 + lm;       // mt=0 pixel; mt=1 is +16

    const float* opb = offs + (((size_t)b * 18) << 16) + (ho << 8) + wo0;
    const unsigned* fpq = (const unsigned*)featp + ((size_t)b << 21) + quad * 4;

    float4v acc[2][4];
#pragma unroll
    for (int mt = 0; mt < 2; mt++)
#pragma unroll
        for (int nt = 0; nt < 4; nt++) acc[mt][nt] = (float4v)0.f;

    float w00[2], w01[2], w10[2], w11[2];
    unsigned e00[2], e01[2], e10[2], e11[2];
    uint4v G[2][4][2];                  // [mt][corner][step], 16B each

    union AFU { short8 v; unsigned u[4]; };

#define COORDS(MT, KY, KX, OY, OX)                                               \
    {                                                                            \
        float sy = (float)(ho - 1 + (KY)) + (OY);                                \
        float sx = (float)(wo0 + (MT) * 16 - 1 + (KX)) + (OX);                   \
        float y0f = floorf(sy), x0f = floorf(sx);                                \
        float dy = sy - y0f, dx = sx - x0f;                                      \
        int y0 = (int)y0f, x0 = (int)x0f;                                        \
        float wy0 = ((unsigned)y0 < 256u) ? (1.f - dy) : 0.f;                    \
        float wy1 = ((unsigned)(y0 + 1) < 256u) ? dy : 0.f;                      \
        float wx0 = ((unsigned)x0 < 256u) ? (1.f - dx) : 0.f;                    \
        float wx1 = ((unsigned)(x0 + 1) < 256u) ? dx : 0.f;                      \
        int yb0 = y0 < 0 ? 0 : (y0 > 255 ? 255 : y0);                            \
        int yb1 = (y0 + 1) < 0 ? 0 : ((y0 + 1) > 255 ? 255 : (y0 + 1));          \
        int xb0 = x0 < 0 ? 0 : (x0 > 255 ? 255 : x0);                            \
        int xb1 = (x0 + 1) < 0 ? 0 : ((x0 + 1) > 255 ? 255 : (x0 + 1));          \
        w00[MT] = wy0 * wx0; w01[MT] = wy0 * wx1;                                \
        w10[MT] = wy1 * wx0; w11[MT] = wy1 * wx1;                                \
        e00[MT] = ((yb0 << 8) + xb0) << 5; e01[MT] = ((yb0 << 8) + xb1) << 5;    \
        e10[MT] = ((yb1 << 8) + xb0) << 5; e11[MT] = ((yb1 << 8) + xb1) << 5;    \
    }

#define ISSUE(MT)                                                                \
    {                                                                            \
        G[MT][0][0] = *(const uint4v*)(fpq + e00[MT]);                           \
        G[MT][0][1] = *(const uint4v*)(fpq + e00[MT] + 16);                      \
        G[MT][1][0] = *(const uint4v*)(fpq + e01[MT]);                           \
        G[MT][1][1] = *(const uint4v*)(fpq + e01[MT] + 16);                      \
        G[MT][2][0] = *(const uint4v*)(fpq + e10[MT]);                           \
        G[MT][2][1] = *(const uint4v*)(fpq + e10[MT] + 16);                      \
        G[MT][3][0] = *(const uint4v*)(fpq + e11[MT]);                           \
        G[MT][3][1] = *(const uint4v*)(fpq + e11[MT] + 16);                      \
    }

#define COMBINE(MT, AF)                                                          \
    _Pragma("unroll")                                                            \
    for (int st = 0; st < 2; st++) {                                             \
        _Pragma("unroll")                                                        \
        for (int j = 0; j < 4; j++) {                                            \
            unsigned u0 = G[MT][0][st][j], u1 = G[MT][1][st][j];                 \
            unsigned u2 = G[MT][2][st][j], u3 = G[MT][3][st][j];                 \
            float g0 = w00[MT] * bf_lo(u0) + w01[MT] * bf_lo(u1)                 \
                     + w10[MT] * bf_lo(u2) + w11[MT] * bf_lo(u3);                \
            float g1 = w00[MT] * bf_hi(u0) + w01[MT] * bf_hi(u1)                 \
                     + w10[MT] * bf_hi(u2) + w11[MT] * bf_hi(u3);                \
            AF[st].u[j] = pack_bf16x2(g0, g1);                                   \
        }                                                                        \
    }

#define MFMA_MT(MT, AF)                                                          \
    _Pragma("unroll")                                                            \
    for (int nt = 0; nt < 4; nt++)                                               \
        acc[MT][nt] = __builtin_amdgcn_mfma_f32_16x16x32_bf16(                   \
            AF[0].v, bfr[0][nt], acc[MT][nt], 0, 0, 0);                          \
    _Pragma("unroll")                                                            \
    for (int nt = 0; nt < 4; nt++)                                               \
        acc[MT][nt] = __builtin_amdgcn_mfma_f32_16x16x32_bf16(                   \
            AF[1].v, bfr[1][nt], acc[MT][nt], 0, 0, 0);

    // Prologue: gather tap 0 for both mt
    {
        float oy0 = opb[0],  ox0 = opb[65536];
        float oy1 = opb[16], ox1 = opb[65536 + 16];
        COORDS(0, 0, 0, oy0, ox0);
        ISSUE(0);
        COORDS(1, 0, 0, oy1, ox1);
        ISSUE(1);
    }

    for (int tap = 0; tap < 9; ++tap) {
        float ny0 = 0.f, nx0 = 0.f, ny1 = 0.f, nx1 = 0.f;
        if (tap < 8) {                                  // next-tap offsets, early
            const float* p = opb + ((size_t)(2 * tap + 2) << 16);
            ny0 = p[0]; ny1 = p[16];
            nx0 = p[65536]; nx1 = p[65536 + 16];
        }
        short8 bfr[2][4];                               // B-frags, both steps
        {
            const unsigned short* wp = wtf + (size_t)tap * 4096 + lane * 8;
#pragma unroll
            for (int nt = 0; nt < 4; nt++) {
                bfr[0][nt] = *(const short8*)(wp + (nt << 9));
                bfr[1][nt] = *(const short8*)(wp + 2048 + (nt << 9));
            }
        }
        const int tn  = tap + 1;
        const int nky = (int)((unsigned)tn / 3u);
        const int nkx = tn - 3 * nky;

        AFU af[2];
        COMBINE(0, af);                                 // G0 issued last tap
        MFMA_MT(0, af);
        if (tap < 8) { COORDS(0, nky, nkx, ny0, nx0); ISSUE(0); }
        COMBINE(1, af);                                 // G1 issued last tap
        MFMA_MT(1, af);
        if (tap < 8) { COORDS(1, nky, nkx, ny1, nx1); ISSUE(1); }
    }

#pragma unroll
    for (int nt = 0; nt < 4; nt++) {
        int oc = nt * 16 + lm;
        float bv = db[oc];
        float* op = out + (((size_t)(b * 64 + oc)) << 16) + (ho << 8)
                  + wo_base + wave * 32 + quad * 4;
#pragma unroll
        for (int mt = 0; mt < 2; mt++) {
            float4 v = {acc[mt][nt][0] + bv, acc[mt][nt][1] + bv,
                        acc[mt][nt][2] + bv, acc[mt][nt][3] + bv};
            *(float4*)(op + mt * 16) = v;
        }
    }
#undef COORDS
#undef ISSUE
#undef COMBINE
#undef MFMA_MT
}

// ---------------------------------------------------------------------------
extern "C" void kernel_launch(void* const* d_in, const int* in_sizes, int n_in,
                              void* d_out, int out_size, void* d_ws, size_t ws_size,
                              hipStream_t stream) {
    const float* x  = (const float*)d_in[0];
    const float* cw = (const float*)d_in[1];
    const float* cb = (const float*)d_in[2];
    const float* ow = (const float*)d_in[3];
    const float* ob = (const float*)d_in[4];
    const float* dw = (const float*)d_in[5];
    const float* db = (const float*)d_in[6];
    float* out = (float*)d_out;

    unsigned short* featp = (unsigned short*)d_ws;       // 33.5 MB bf16 NHWC
    float* offsb = (float*)(featp + FEAT_N);             // 18 MB
    unsigned short* wtf  = (unsigned short*)(offsb + OFFS_N);  // 72 KB
    unsigned short* wt2f = wtf + WTF_N;                  // 36 KB

    prep_weights<<<216, 256, 0, stream>>>(dw, ow, wtf, wt2f);
    conv1_kernel<<<1024, 256, 0, stream>>>(x, cw, cb, featp);
    conv2_kernel<<<2048, 256, 0, stream>>>(featp, wt2f, ob, offsb);
    deform_kernel<<<2048, 256, 0, stream>>>(featp, offsb, wtf, db, out);
}